// Round 2
// baseline (463.644 us; speedup 1.0000x reference)
//
#include <hip/hip_runtime.h>

// Problem constants (from reference): B=8, E=4096, H=32, D=128, L=4095
#define EDIM 4096
#define NB 8
#define NH 32
#define HD 128
#define LCACHE 4095.0f

// -----------------------------------------------------------------------------
// proj2_kernel: out[m][b][row] = sum_e x[b][e] * Wm[row][e]
//
// Memory-bound batched matvec (rank-8 GEMV). Design goals, in order:
//   1. Every W load is a wave-contiguous float4 load (64 lanes x 16B = 1KB,
//      perfectly coalesced -- the pattern that hits ~6.3 TB/s).
//   2. No atomics, no cross-wave reduction: each WAVE owns RPW complete rows,
//      keeps 8 batch-accumulators per lane, and reduces them with a 10-shuffle
//      in-register butterfly at the end. One coalesced store per output.
//   3. x lives in LDS, staged in two 64KB halves (8 batches x 2048 floats),
//      so LDS stays at 64KB/block -> 2 blocks/CU -> 16 waves/CU.
//
// Work partition (no tail): grid 512 x 8 waves x RPW rows.
//   kernel1: RPW=3 -> 12288 rows (Wq,Wk,Wv).  kernel2: RPW=1 -> 4096 rows (Wo).
// -----------------------------------------------------------------------------
template<int RPW>
__global__ __launch_bounds__(512, 4)
void proj2_kernel(const float* __restrict__ x,
                  const float* __restrict__ W0,
                  const float* __restrict__ W1,
                  const float* __restrict__ W2,
                  float* __restrict__ out)
{
    __shared__ float4 xlds4[4096];      // 64KB: x[b][e-half] as [8][512] float4
    const int tid  = threadIdx.x;
    const int lane = tid & 63;
    const int wid  = tid >> 6;          // 0..7

    const int rg0 = (blockIdx.x * 8 + wid) * RPW;

    const float4* Wp[RPW];
    int mArr[RPW], rowArr[RPW];
#pragma unroll
    for (int r = 0; r < RPW; ++r) {
        const int rg  = rg0 + r;
        const int m   = rg >> 12;            // matrix select
        const int row = rg & (EDIM - 1);
        mArr[r] = m; rowArr[r] = row;
        const float* W = (m == 0) ? W0 : ((m == 1) ? W1 : W2);
        Wp[r] = (const float4*)(W + (size_t)row * EDIM);
    }

    float acc[RPW][8];
#pragma unroll
    for (int r = 0; r < RPW; ++r)
#pragma unroll
        for (int b = 0; b < 8; ++b) acc[r][b] = 0.0f;

    const float4* x4 = (const float4*)x;

    for (int h = 0; h < 2; ++h) {
        __syncthreads();                 // all waves done with previous half
        for (int k = tid; k < 4096; k += 512) {
            // x layout: [b][1024] float4; half h takes float4s [h*512, h*512+512)
            xlds4[k] = x4[(k >> 9) * 1024 + h * 512 + (k & 511)];
        }
        __syncthreads();

#pragma unroll
        for (int i = 0; i < 8; ++i) {
            float4 w[RPW];
#pragma unroll
            for (int r = 0; r < RPW; ++r)
                w[r] = Wp[r][h * 512 + i * 64 + lane];    // coalesced 1KB/wave
#pragma unroll
            for (int b = 0; b < 8; ++b) {
                const float4 xv = xlds4[b * 512 + i * 64 + lane];
#pragma unroll
                for (int r = 0; r < RPW; ++r)
                    acc[r][b] += w[r].x * xv.x + w[r].y * xv.y +
                                 w[r].z * xv.z + w[r].w * xv.w;
            }
        }
    }

    // Butterfly reduction: fold the 8 per-lane batch accumulators across the
    // 64 lanes. After xor{1,2,4} each lane holds the group-of-8 partial for
    // batch b = 4*bit0(lane) + 2*bit1(lane) + bit2(lane); xor{8,16,32} then
    // sums across the 8 groups.
#pragma unroll
    for (int r = 0; r < RPW; ++r) {
        float v[8];
#pragma unroll
        for (int b = 0; b < 8; ++b) v[b] = acc[r][b];

#pragma unroll
        for (int j = 0; j < 4; ++j) {
            float send = (lane & 1) ? v[j] : v[j + 4];
            float rcv  = __shfl_xor(send, 1, 64);
            v[j] = ((lane & 1) ? v[j + 4] : v[j]) + rcv;
        }
#pragma unroll
        for (int j = 0; j < 2; ++j) {
            float send = (lane & 2) ? v[j] : v[j + 2];
            float rcv  = __shfl_xor(send, 2, 64);
            v[j] = ((lane & 2) ? v[j + 2] : v[j]) + rcv;
        }
        {
            float send = (lane & 4) ? v[0] : v[1];
            float rcv  = __shfl_xor(send, 4, 64);
            v[0] = ((lane & 4) ? v[1] : v[0]) + rcv;
        }
        float t = v[0];
        t += __shfl_xor(t, 8, 64);
        t += __shfl_xor(t, 16, 64);
        t += __shfl_xor(t, 32, 64);

        if (lane < 8) {
            const int b = ((lane & 1) << 2) | (lane & 2) | ((lane >> 2) & 1);
            out[(size_t)mArr[r] * (NB * EDIM) + (size_t)b * EDIM + rowArr[r]] = t;
        }
    }
}

// -----------------------------------------------------------------------------
// attn_kernel: closed form of the ones-cache attention (numerically exact).
//   s0 = sum(q)/sqrt(D)   -- score of each of the 4095 all-ones cache slots
//   s1 = dot(q,k)/sqrt(D) -- score of the appended position
//   o_d = (4095*e0 + e1*v_d) / (4095*e0 + e1),  e = exp(s - max)
// One block (128 threads = D) per (b,h).
// -----------------------------------------------------------------------------
__global__ __launch_bounds__(128)
void attn_kernel(const float* __restrict__ qkv, float* __restrict__ o)
{
    const int bh = blockIdx.x;              // b*32 + h
    const int d  = threadIdx.x;             // 0..127
    const int off = (bh >> 5) * EDIM + (bh & 31) * HD + d;

    const float* q = qkv;
    const float* k = qkv + NB * EDIM;
    const float* v = qkv + 2 * NB * EDIM;

    const float qd = q[off];
    const float kd = k[off];
    const float vd = v[off];

    float s1p = qd;
    float s2p = qd * kd;
#pragma unroll
    for (int m = 1; m < 64; m <<= 1) {
        s1p += __shfl_xor(s1p, m, 64);
        s2p += __shfl_xor(s2p, m, 64);
    }

    __shared__ float l1[2], l2[2];
    const int wid = d >> 6;
    if ((d & 63) == 0) { l1[wid] = s1p; l2[wid] = s2p; }
    __syncthreads();

    const float sq  = l1[0] + l1[1];
    const float sqk = l2[0] + l2[1];

    const float scale = 0.08838834764831843f;   // 1/sqrt(128)
    const float s0 = sq  * scale;
    const float s1 = sqk * scale;
    const float mx = fmaxf(s0, s1);
    const float e0 = expf(s0 - mx);
    const float e1 = expf(s1 - mx);
    const float Z  = LCACHE * e0 + e1;

    o[off] = (LCACHE * e0 + e1 * vd) / Z;
}

// -----------------------------------------------------------------------------
// kernel_launch
// d_in: [x (8*1*4096), Wq, Wk, Wv, Wo (each 4096*4096)], all f32.
// d_out: 8*4096 f32.  Workspace (floats): q[8][4096], k[..], v[..], o[..]
// All outputs are fully overwritten (no atomics) -> no memsets needed.
// -----------------------------------------------------------------------------
extern "C" void kernel_launch(void* const* d_in, const int* in_sizes, int n_in,
                              void* d_out, int out_size, void* d_ws, size_t ws_size,
                              hipStream_t stream)
{
    const float* x  = (const float*)d_in[0];
    const float* Wq = (const float*)d_in[1];
    const float* Wk = (const float*)d_in[2];
    const float* Wv = (const float*)d_in[3];
    const float* Wo = (const float*)d_in[4];
    float* out  = (float*)d_out;
    float* qkv  = (float*)d_ws;                  // 3 * 8 * 4096 floats
    float* obuf = qkv + 3 * NB * EDIM;           // 8 * 4096 floats

    // q,k,v projections: 512 blocks x 8 waves x 3 rows = 12288 rows
    proj2_kernel<3><<<512, 512, 0, stream>>>(x, Wq, Wk, Wv, qkv);

    // attention closed form -> o
    attn_kernel<<<NB * NH, 128, 0, stream>>>(qkv, obuf);

    // out-projection: 512 x 8 x 1 = 4096 rows, writes d_out directly
    proj2_kernel<1><<<512, 512, 0, stream>>>(obuf, Wo, Wo, Wo, out);
}

// Round 4
// 250.710 us; speedup vs baseline: 1.8493x; 1.8493x over previous
//
#include <hip/hip_runtime.h>

// Problem constants (from reference): B=8, E=4096, H=32, D=128, L=4095
#define EDIM 4096
#define NB 8
#define NH 32
#define HD 128
#define LCACHE 4095.0f

// -----------------------------------------------------------------------------
// proj2_kernel: out[m][b][row] = sum_e x[b][e] * Wm[row][e]
//
// Memory-bound batched matvec (rank-8 GEMV).
//   1. Every W load is a wave-contiguous float4 load (64 lanes x 16B = 1KB).
//   2. No atomics / no cross-wave reduction: each WAVE owns RPW complete rows,
//      8 batch-accumulators per lane, 10-shuffle butterfly at the end.
//   3. x staged in LDS in two 64KB halves -> 2 blocks/CU, 16 waves/CU.
//
// Anti-spill (round 3):
//   - __launch_bounds__(512, 2): round 2's (512,4) capped VGPRs at 64 and the
//     kernel spilled ~520MB of scratch traffic per dispatch (WRITE_SIZE 395MB
//     vs 384KB of real output). (512,2) allows 128 VGPRs; occupancy is
//     LDS-capped at 2 blocks/CU regardless.
//   - `#pragma unroll 2` on the i-loop (was full unroll): caps in-flight W
//     loads at 6/wave (~70 live VGPRs) instead of 24 (~130+).
// -----------------------------------------------------------------------------
template<int RPW>
__global__ __launch_bounds__(512, 2)
void proj2_kernel(const float* __restrict__ x,
                  const float* __restrict__ W0,
                  const float* __restrict__ W1,
                  const float* __restrict__ W2,
                  float* __restrict__ out)
{
    __shared__ float4 xlds4[4096];      // 64KB: x[b][e-half] as [8][512] float4
    const int tid  = threadIdx.x;
    const int lane = tid & 63;
    const int wid  = tid >> 6;          // 0..7

    const int rg0 = (blockIdx.x * 8 + wid) * RPW;

    const float4* Wp[RPW];
    int mArr[RPW], rowArr[RPW];
#pragma unroll
    for (int r = 0; r < RPW; ++r) {
        const int rg  = rg0 + r;
        const int m   = rg >> 12;            // matrix select
        const int row = rg & (EDIM - 1);
        mArr[r] = m; rowArr[r] = row;
        const float* W = (m == 0) ? W0 : ((m == 1) ? W1 : W2);
        Wp[r] = (const float4*)(W + (size_t)row * EDIM);
    }

    float acc[RPW][8];
#pragma unroll
    for (int r = 0; r < RPW; ++r)
#pragma unroll
        for (int b = 0; b < 8; ++b) acc[r][b] = 0.0f;

    const float4* x4 = (const float4*)x;

    for (int h = 0; h < 2; ++h) {
        __syncthreads();                 // all waves done with previous half
        for (int k = tid; k < 4096; k += 512) {
            // x layout: [b][1024] float4; half h takes float4s [h*512, h*512+512)
            xlds4[k] = x4[(k >> 9) * 1024 + h * 512 + (k & 511)];
        }
        __syncthreads();

#pragma unroll 2
        for (int i = 0; i < 8; ++i) {
            float4 w[RPW];
#pragma unroll
            for (int r = 0; r < RPW; ++r)
                w[r] = Wp[r][h * 512 + i * 64 + lane];    // coalesced 1KB/wave
#pragma unroll
            for (int b = 0; b < 8; ++b) {
                const float4 xv = xlds4[b * 512 + i * 64 + lane];
#pragma unroll
                for (int r = 0; r < RPW; ++r)
                    acc[r][b] += w[r].x * xv.x + w[r].y * xv.y +
                                 w[r].z * xv.z + w[r].w * xv.w;
            }
        }
    }

    // Butterfly reduction: fold the 8 per-lane batch accumulators across the
    // 64 lanes. After xor{1,2,4} each lane holds the group-of-8 partial for
    // batch b = 4*bit0(lane) + 2*bit1(lane) + bit2(lane); xor{8,16,32} then
    // sums across the 8 groups.
#pragma unroll
    for (int r = 0; r < RPW; ++r) {
        float v[8];
#pragma unroll
        for (int b = 0; b < 8; ++b) v[b] = acc[r][b];

#pragma unroll
        for (int j = 0; j < 4; ++j) {
            float send = (lane & 1) ? v[j] : v[j + 4];
            float rcv  = __shfl_xor(send, 1, 64);
            v[j] = ((lane & 1) ? v[j + 4] : v[j]) + rcv;
        }
#pragma unroll
        for (int j = 0; j < 2; ++j) {
            float send = (lane & 2) ? v[j] : v[j + 2];
            float rcv  = __shfl_xor(send, 2, 64);
            v[j] = ((lane & 2) ? v[j + 2] : v[j]) + rcv;
        }
        {
            float send = (lane & 4) ? v[0] : v[1];
            float rcv  = __shfl_xor(send, 4, 64);
            v[0] = ((lane & 4) ? v[1] : v[0]) + rcv;
        }
        float t = v[0];
        t += __shfl_xor(t, 8, 64);
        t += __shfl_xor(t, 16, 64);
        t += __shfl_xor(t, 32, 64);

        if (lane < 8) {
            const int b = ((lane & 1) << 2) | (lane & 2) | ((lane >> 2) & 1);
            out[(size_t)mArr[r] * (NB * EDIM) + (size_t)b * EDIM + rowArr[r]] = t;
        }
    }
}

// -----------------------------------------------------------------------------
// attn_kernel: closed form of the ones-cache attention (numerically exact).
//   s0 = sum(q)/sqrt(D)   -- score of each of the 4095 all-ones cache slots
//   s1 = dot(q,k)/sqrt(D) -- score of the appended position
//   o_d = (4095*e0 + e1*v_d) / (4095*e0 + e1),  e = exp(s - max)
// One block (128 threads = D) per (b,h).
// -----------------------------------------------------------------------------
__global__ __launch_bounds__(128)
void attn_kernel(const float* __restrict__ qkv, float* __restrict__ o)
{
    const int bh = blockIdx.x;              // b*32 + h
    const int d  = threadIdx.x;             // 0..127
    const int off = (bh >> 5) * EDIM + (bh & 31) * HD + d;

    const float* q = qkv;
    const float* k = qkv + NB * EDIM;
    const float* v = qkv + 2 * NB * EDIM;

    const float qd = q[off];
    const float kd = k[off];
    const float vd = v[off];

    float s1p = qd;
    float s2p = qd * kd;
#pragma unroll
    for (int m = 1; m < 64; m <<= 1) {
        s1p += __shfl_xor(s1p, m, 64);
        s2p += __shfl_xor(s2p, m, 64);
    }

    __shared__ float l1[2], l2[2];
    const int wid = d >> 6;
    if ((d & 63) == 0) { l1[wid] = s1p; l2[wid] = s2p; }
    __syncthreads();

    const float sq  = l1[0] + l1[1];
    const float sqk = l2[0] + l2[1];

    const float scale = 0.08838834764831843f;   // 1/sqrt(128)
    const float s0 = sq  * scale;
    const float s1 = sqk * scale;
    const float mx = fmaxf(s0, s1);
    const float e0 = expf(s0 - mx);
    const float e1 = expf(s1 - mx);
    const float Z  = LCACHE * e0 + e1;

    o[off] = (LCACHE * e0 + e1 * vd) / Z;
}

// -----------------------------------------------------------------------------
// kernel_launch
// d_in: [x (8*1*4096), Wq, Wk, Wv, Wo (each 4096*4096)], all f32.
// d_out: 8*4096 f32.  Workspace (floats): q[8][4096], k[..], v[..], o[..]
// All outputs are fully overwritten (no atomics) -> no memsets needed.
// -----------------------------------------------------------------------------
extern "C" void kernel_launch(void* const* d_in, const int* in_sizes, int n_in,
                              void* d_out, int out_size, void* d_ws, size_t ws_size,
                              hipStream_t stream)
{
    const float* x  = (const float*)d_in[0];
    const float* Wq = (const float*)d_in[1];
    const float* Wk = (const float*)d_in[2];
    const float* Wv = (const float*)d_in[3];
    const float* Wo = (const float*)d_in[4];
    float* out  = (float*)d_out;
    float* qkv  = (float*)d_ws;                  // 3 * 8 * 4096 floats
    float* obuf = qkv + 3 * NB * EDIM;           // 8 * 4096 floats

    // q,k,v projections: 512 blocks x 8 waves x 3 rows = 12288 rows
    proj2_kernel<3><<<512, 512, 0, stream>>>(x, Wq, Wk, Wv, qkv);

    // attention closed form -> o
    attn_kernel<<<NB * NH, 128, 0, stream>>>(qkv, obuf);

    // out-projection: 512 x 8 x 1 = 4096 rows, writes d_out directly
    proj2_kernel<1><<<512, 512, 0, stream>>>(obuf, Wo, Wo, Wo, out);
}